// Round 1
// baseline (997.539 us; speedup 1.0000x reference)
//
#include <hip/hip_runtime.h>
#include <math.h>

#define NCH   14595
#define WROW  14596          // padded row stride (floats) in transposed workspace -> 16B-aligned rows
#define HR_C  13
#define IMG_H 512
#define IMG_W 512
#define BS    4

// layer table: params laid out per layer as [bias(nco) | W(nci*nco)], contiguous
// starts: L0:0 (1920), L1:1920 (4160), L2:6080 (4160), L3:10240 (4160), L4:14400 (195)

__global__ __launch_bounds__(256) void transpose_params(const float* __restrict__ lp,
                                                        float* __restrict__ wsT) {
    // lp: [BS][NCH][1024] -> wsT: [BS][1024][WROW]
    __shared__ float tile[64][65];
    int bid = blockIdx.x;
    int pt = bid & 15;               // 16 p-tiles of 64
    int t  = bid >> 4;
    int ct = t % 229;                // 229 c-tiles of 64 (14595 -> guard)
    int b  = t / 229;
    int c0 = ct * 64, p0 = pt * 64;
    int tp = threadIdx.x & 63;
    int tr = threadIdx.x >> 6;       // 0..3
#pragma unroll
    for (int s = 0; s < 16; s++) {
        int c = c0 + tr + s * 4;
        if (c < NCH)
            tile[tr + s * 4][tp] = lp[((size_t)b * NCH + c) * 1024 + p0 + tp];
    }
    __syncthreads();
#pragma unroll
    for (int s = 0; s < 16; s++) {
        int p = p0 + tr + s * 4;
        int c = c0 + tp;
        if (c < NCH)
            wsT[((size_t)b * 1024 + p) * WROW + c] = tile[tp][tr + s * 4];
    }
}

__global__ __launch_bounds__(256) void asap_main(const float* __restrict__ hr,
                                                 const float* __restrict__ lp,
                                                 const float* __restrict__ wsT,
                                                 float* __restrict__ out,
                                                 int use_ws) {
    __shared__ __align__(16) float actT[64 * 128];   // [ch][px] fp32, 32 KB
    __shared__ __align__(16) float wbuf[4160];       // current layer [bias|W], 16.6 KB

    // XCD-chunked swizzle (8192 blocks, 1024 per XCD, bijective)
    int bid0 = blockIdx.x;
    int bid  = ((bid0 & 7) << 10) | (bid0 >> 3);

    int half = bid & 1;
    int x    = (bid >> 1) & 31;
    int y    = (bid >> 6) & 31;
    int b    = bid >> 11;
    int tid  = threadIdx.x;
    int pix  = y * 32 + x;

    const int lstart[5] = {0, 1920, 6080, 10240, 14400};
    const int llen[5]   = {1920, 4160, 4160, 4160, 195};

    auto stage = [&](int off, int len) {
        if (use_ws) {
            const float* src = wsT + ((size_t)b * 1024 + pix) * WROW + off;
            int n4 = len >> 2;
            const float4* s4 = (const float4*)src;
            float4* d4 = (float4*)wbuf;
            for (int j = tid; j < n4; j += 256) d4[j] = s4[j];
            for (int j = (n4 << 2) + tid; j < len; j += 256) wbuf[j] = src[j];
        } else {
            const float* src = lp + (size_t)b * NCH * 1024 + pix;
            for (int j = tid; j < len; j += 256)
                wbuf[j] = src[(size_t)(off + j) << 10];
        }
    };

    // ---- stage layer-0 weights + inputs ----
    stage(0, 1920);
    {
        int Y0 = y * 16 + half * 8, X0 = x * 16;
        for (int t = tid; t < HR_C * 128; t += 256) {
            int c = t >> 7, p = t & 127;
            int row = p >> 4, kx = p & 15;
            actT[c * 128 + p] =
                hr[(((size_t)b * HR_C + c) * IMG_H + Y0 + row) * IMG_W + X0 + kx];
        }
        if (tid < 128) {
            int p = tid, row = p >> 4, kx = p & 15;
            int kyg = half * 8 + row;
            const float two_pi = 6.28318530717958647692f;
            int f = 16;
#pragma unroll
            for (int fi = 0; fi < 4; fi++) {
                float ax = two_pi * (float)(kx & (f - 1)) / (float)f;
                float ay = two_pi * (float)(kyg & (f - 1)) / (float)f;
                actT[(13 + 4 * fi + 0) * 128 + p] = cosf(ax);
                actT[(13 + 4 * fi + 1) * 128 + p] = sinf(ax);
                actT[(13 + 4 * fi + 2) * 128 + p] = cosf(ay);
                actT[(13 + 4 * fi + 3) * 128 + p] = sinf(ay);
                f >>= 1;
            }
        }
    }

    int pg = tid & 31, og = tid >> 5;
    int px0 = pg << 2, o0 = og << 3;
    float acc[4][8];

    // ---- hidden layers 0..3 (nco=64) ----
#pragma unroll 1
    for (int l = 0; l < 4; l++) {
        int nci = (l == 0) ? 29 : 64;
        __syncthreads();   // actT + wbuf ready
#pragma unroll
        for (int j = 0; j < 8; j++) {
            float bv = wbuf[o0 + j];
            acc[0][j] = bv; acc[1][j] = bv; acc[2][j] = bv; acc[3][j] = bv;
        }
        for (int k = 0; k < nci; k++) {
            float4 a  = *(const float4*)&actT[k * 128 + px0];
            float4 w0 = *(const float4*)&wbuf[64 + (k << 6) + o0];
            float4 w1 = *(const float4*)&wbuf[64 + (k << 6) + o0 + 4];
            float av[4] = {a.x, a.y, a.z, a.w};
            float wv[8] = {w0.x, w0.y, w0.z, w0.w, w1.x, w1.y, w1.z, w1.w};
#pragma unroll
            for (int i = 0; i < 4; i++)
#pragma unroll
                for (int j = 0; j < 8; j++)
                    acc[i][j] = fmaf(av[i], wv[j], acc[i][j]);
        }
        __syncthreads();   // all reads of actT/wbuf done
#pragma unroll
        for (int j = 0; j < 8; j++) {
            float4 v;
            v.x = acc[0][j]; v.y = acc[1][j]; v.z = acc[2][j]; v.w = acc[3][j];
            v.x = v.x >= 0.f ? v.x : 0.01f * v.x;
            v.y = v.y >= 0.f ? v.y : 0.01f * v.y;
            v.z = v.z >= 0.f ? v.z : 0.01f * v.z;
            v.w = v.w >= 0.f ? v.w : 0.01f * v.w;
            *(float4*)&actT[(o0 + j) * 128 + px0] = v;
        }
        stage(lstart[l + 1], llen[l + 1]);   // next layer weights (disjoint LDS region)
    }
    __syncthreads();

    // ---- final layer: nci=64, nco=3, tanh ----
    if (tid < 128) {
        int p = tid;
        float s0 = wbuf[0], s1 = wbuf[1], s2 = wbuf[2];
        for (int k = 0; k < 64; k++) {
            float a = actT[k * 128 + p];
            s0 = fmaf(a, wbuf[3 + k * 3 + 0], s0);
            s1 = fmaf(a, wbuf[3 + k * 3 + 1], s1);
            s2 = fmaf(a, wbuf[3 + k * 3 + 2], s2);
        }
        int row = p >> 4, kx = p & 15;
        int Y = y * 16 + half * 8 + row, X = x * 16 + kx;
        size_t base = ((size_t)b * 3) * IMG_H * IMG_W + (size_t)Y * IMG_W + X;
        out[base]                         = tanhf(s0);
        out[base + (size_t)IMG_H * IMG_W]     = tanhf(s1);
        out[base + (size_t)2 * IMG_H * IMG_W] = tanhf(s2);
    }
}

extern "C" void kernel_launch(void* const* d_in, const int* in_sizes, int n_in,
                              void* d_out, int out_size, void* d_ws, size_t ws_size,
                              hipStream_t stream) {
    const float* hr = (const float*)d_in[0];
    const float* lp = (const float*)d_in[1];
    float* out = (float*)d_out;
    float* wsT = (float*)d_ws;

    size_t need = (size_t)BS * 1024 * WROW * sizeof(float);
    int use_ws = (ws_size >= need) ? 1 : 0;

    if (use_ws) {
        transpose_params<<<BS * 229 * 16, 256, 0, stream>>>(lp, wsT);
    }
    asap_main<<<8192, 256, 0, stream>>>(hr, lp, wsT, out, use_ws);
}

// Round 2
// 533.865 us; speedup vs baseline: 1.8685x; 1.8685x over previous
//
#include <hip/hip_runtime.h>
#include <math.h>

#define NCH   14595
#define WROW  14596          // padded row stride (floats) in transposed workspace
#define HR_C  13
#define IMG_H 512
#define IMG_W 512
#define BS    4

// param layout per lr-pixel: [bias|W] per layer, starts:
// L0:0 (1920), L1:1920 (4160), L2:6080 (4160), L3:10240 (4160), L4:14400 (195)

__global__ __launch_bounds__(256) void transpose_params(const float* __restrict__ lp,
                                                        float* __restrict__ wsT) {
    // lp: [BS][NCH][1024] -> wsT: [BS][1024][WROW]
    __shared__ float tile[64][65];
    int bid = blockIdx.x;
    int pt = bid & 15;
    int t  = bid >> 4;
    int ct = t % 229;
    int b  = t / 229;
    int c0 = ct * 64, p0 = pt * 64;
    int tp = threadIdx.x & 63;
    int tr = threadIdx.x >> 6;
#pragma unroll
    for (int s = 0; s < 16; s++) {
        int c = c0 + tr + s * 4;
        if (c < NCH)
            tile[tr + s * 4][tp] = lp[((size_t)b * NCH + c) * 1024 + p0 + tp];
    }
    __syncthreads();
#pragma unroll
    for (int s = 0; s < 16; s++) {
        int p = p0 + tr + s * 4;
        int c = c0 + tp;
        if (c < NCH)
            wsT[((size_t)b * 1024 + p) * WROW + c] = tile[tp][tr + s * 4];
    }
}

// Barrier that orders LDS only — does NOT drain vmcnt, so global loads
// issued into registers stay in flight across it (async staging).
__device__ __forceinline__ void block_sync_lds() {
    __builtin_amdgcn_sched_barrier(0);
    asm volatile("s_waitcnt lgkmcnt(0)" ::: "memory");
    __builtin_amdgcn_s_barrier();
    __builtin_amdgcn_sched_barrier(0);
}

template<int NCI>
__device__ __forceinline__ void mlp_layer(const float* __restrict__ actT,
                                          const float* __restrict__ wbuf,
                                          int px0, int o0, float acc[4][8]) {
#pragma unroll
    for (int j = 0; j < 8; j++) {
        float bv = wbuf[o0 + j];
        acc[0][j] = bv; acc[1][j] = bv; acc[2][j] = bv; acc[3][j] = bv;
    }
#pragma unroll 4
    for (int k = 0; k < NCI; k++) {
        float4 a  = *(const float4*)&actT[k * 128 + px0];
        float4 w0 = *(const float4*)&wbuf[64 + (k << 6) + o0];
        float4 w1 = *(const float4*)&wbuf[64 + (k << 6) + o0 + 4];
        float av[4] = {a.x, a.y, a.z, a.w};
        float wv[8] = {w0.x, w0.y, w0.z, w0.w, w1.x, w1.y, w1.z, w1.w};
#pragma unroll
        for (int i = 0; i < 4; i++)
#pragma unroll
            for (int j = 0; j < 8; j++)
                acc[i][j] = fmaf(av[i], wv[j], acc[i][j]);
    }
}

__global__ __launch_bounds__(256, 3) void asap_main(const float* __restrict__ hr,
                                                    const float* __restrict__ lp,
                                                    const float* __restrict__ wsT,
                                                    float* __restrict__ out,
                                                    int use_ws) {
    __shared__ __align__(16) float actT[64 * 128];   // [ch][px] fp32, 32 KB
    __shared__ __align__(16) float wbuf[4160];       // current layer [bias|W], 16.6 KB

    // XCD-chunked swizzle (8192 blocks, 1024 per XCD, bijective)
    int bid0 = blockIdx.x;
    int bid  = ((bid0 & 7) << 10) | (bid0 >> 3);

    int half = bid & 1;
    int x    = (bid >> 1) & 31;
    int y    = (bid >> 6) & 31;
    int b    = bid >> 11;
    int tid  = threadIdx.x;
    int pix  = y * 32 + x;

    const size_t wrow_base = ((size_t)b * 1024 + pix) * WROW;
    const float* lp_base   = lp + (size_t)b * NCH * 1024 + pix;

    // ---- async register staging of a layer's [bias|W] slice ----
    float4 rv[5];
    float  rt0 = 0.f;
    auto stage_load = [&](int off, int len) {
        int n4 = len >> 2;
        if (use_ws) {
            const float4* s4 = (const float4*)(wsT + wrow_base + off);
#pragma unroll
            for (int i = 0; i < 5; i++) {
                int j = tid + (i << 8);
                if (j < n4) rv[i] = s4[j];
            }
            if (tid < (len & 3)) rt0 = wsT[wrow_base + off + (len & ~3) + tid];
        } else {
#pragma unroll
            for (int i = 0; i < 5; i++) {
                int j = tid + (i << 8);
                if (j < n4) {
                    int e = off + (j << 2);
                    rv[i].x = lp_base[(size_t)(e + 0) << 10];
                    rv[i].y = lp_base[(size_t)(e + 1) << 10];
                    rv[i].z = lp_base[(size_t)(e + 2) << 10];
                    rv[i].w = lp_base[(size_t)(e + 3) << 10];
                }
            }
            if (tid < (len & 3)) rt0 = lp_base[(size_t)(off + (len & ~3) + tid) << 10];
        }
    };
    auto stage_store = [&](int len) {
        int n4 = len >> 2;
        float4* d4 = (float4*)wbuf;
#pragma unroll
        for (int i = 0; i < 5; i++) {
            int j = tid + (i << 8);
            if (j < n4) d4[j] = rv[i];
        }
        if (tid < (len & 3)) wbuf[(len & ~3) + tid] = rt0;
    };

    // ---- stage layer-0 weights (direct to LDS) + build inputs ----
    {
        if (use_ws) {
            const float4* s4 = (const float4*)(wsT + wrow_base);
            float4* d4 = (float4*)wbuf;
            for (int j = tid; j < 480; j += 256) d4[j] = s4[j];
        } else {
            for (int j = tid; j < 1920; j += 256) wbuf[j] = lp_base[(size_t)j << 10];
        }
        int Y0 = y * 16 + half * 8, X0 = x * 16;
        for (int t = tid; t < HR_C * 128; t += 256) {
            int c = t >> 7, p = t & 127;
            int row = p >> 4, kx = p & 15;
            actT[c * 128 + p] =
                hr[(((size_t)b * HR_C + c) * IMG_H + Y0 + row) * IMG_W + X0 + kx];
        }
        if (tid < 128) {
            int p = tid, row = p >> 4, kx = p & 15;
            int kyg = half * 8 + row;
            const float two_pi = 6.28318530717958647692f;
            int f = 16;
#pragma unroll
            for (int fi = 0; fi < 4; fi++) {
                float ax = two_pi * (float)(kx & (f - 1)) / (float)f;
                float ay = two_pi * (float)(kyg & (f - 1)) / (float)f;
                actT[(13 + 4 * fi + 0) * 128 + p] = cosf(ax);
                actT[(13 + 4 * fi + 1) * 128 + p] = sinf(ax);
                actT[(13 + 4 * fi + 2) * 128 + p] = cosf(ay);
                actT[(13 + 4 * fi + 3) * 128 + p] = sinf(ay);
                f >>= 1;
            }
        }
    }
    block_sync_lds();

    int pg = tid & 31, og = tid >> 5;
    int px0 = pg << 2, o0 = og << 3;
    float acc[4][8];

    auto writeback = [&]() {
#pragma unroll
        for (int j = 0; j < 8; j++) {
            float4 v;
            v.x = acc[0][j]; v.y = acc[1][j]; v.z = acc[2][j]; v.w = acc[3][j];
            v.x = v.x >= 0.f ? v.x : 0.01f * v.x;
            v.y = v.y >= 0.f ? v.y : 0.01f * v.y;
            v.z = v.z >= 0.f ? v.z : 0.01f * v.z;
            v.w = v.w >= 0.f ? v.w : 0.01f * v.w;
            *(float4*)&actT[(o0 + j) * 128 + px0] = v;
        }
    };

    // ---- L0 (nci=29) ----
    stage_load(1920, 4160);                 // L1 weights -> regs (in flight)
    mlp_layer<29>(actT, wbuf, px0, o0, acc);
    block_sync_lds();
    writeback();
    stage_store(4160);
    block_sync_lds();

    // ---- L1 ----
    stage_load(6080, 4160);
    mlp_layer<64>(actT, wbuf, px0, o0, acc);
    block_sync_lds();
    writeback();
    stage_store(4160);
    block_sync_lds();

    // ---- L2 ----
    stage_load(10240, 4160);
    mlp_layer<64>(actT, wbuf, px0, o0, acc);
    block_sync_lds();
    writeback();
    stage_store(4160);
    block_sync_lds();

    // ---- L3 ----
    stage_load(14400, 195);
    mlp_layer<64>(actT, wbuf, px0, o0, acc);
    block_sync_lds();
    writeback();
    stage_store(195);
    block_sync_lds();

    // ---- final layer: nci=64, nco=3, tanh ----
    if (tid < 128) {
        int p = tid;
        float s0 = wbuf[0], s1 = wbuf[1], s2 = wbuf[2];
#pragma unroll 4
        for (int k = 0; k < 64; k++) {
            float a = actT[k * 128 + p];
            s0 = fmaf(a, wbuf[3 + k * 3 + 0], s0);
            s1 = fmaf(a, wbuf[3 + k * 3 + 1], s1);
            s2 = fmaf(a, wbuf[3 + k * 3 + 2], s2);
        }
        int row = p >> 4, kx = p & 15;
        int Y = y * 16 + half * 8 + row, X = x * 16 + kx;
        size_t base = ((size_t)b * 3) * IMG_H * IMG_W + (size_t)Y * IMG_W + X;
        out[base]                             = tanhf(s0);
        out[base + (size_t)IMG_H * IMG_W]     = tanhf(s1);
        out[base + (size_t)2 * IMG_H * IMG_W] = tanhf(s2);
    }
}

extern "C" void kernel_launch(void* const* d_in, const int* in_sizes, int n_in,
                              void* d_out, int out_size, void* d_ws, size_t ws_size,
                              hipStream_t stream) {
    const float* hr = (const float*)d_in[0];
    const float* lp = (const float*)d_in[1];
    float* out = (float*)d_out;
    float* wsT = (float*)d_ws;

    size_t need = (size_t)BS * 1024 * WROW * sizeof(float);
    int use_ws = (ws_size >= need) ? 1 : 0;

    if (use_ws) {
        transpose_params<<<BS * 229 * 16, 256, 0, stream>>>(lp, wsT);
    }
    asap_main<<<8192, 256, 0, stream>>>(hr, lp, wsT, out, use_ws);
}